// Round 11
// baseline (236.195 us; speedup 1.0000x reference)
//
#include <hip/hip_runtime.h>
#include <cmath>
#include <cstdint>
#include <cstddef>

#define N_NODES 50000
#define N_EDGES 800000
#define EN_TOT  (N_EDGES + N_NODES)   // edges + self loops
#define PAD     96                     // bucket capacity (Poisson(17): P(deg>96)~1e-40)
#define F1 256                         // HEADS*HID
#define F2 64                          // OUT

typedef __attribute__((ext_vector_type(8))) short short8;
typedef __attribute__((ext_vector_type(4))) float float4v;

__device__ __forceinline__ float bf2f(unsigned short u) {
    return __uint_as_float((unsigned)u << 16);
}
__device__ __forceinline__ unsigned short f2bf(float f) {
    unsigned u = __float_as_uint(f);
    unsigned r = (u + 0x7FFFu + ((u >> 16) & 1u)) >> 16;   // round-nearest-even
    return (unsigned short)r;
}
__device__ __forceinline__ float lrelu(float x) { return x > 0.f ? x : 0.2f * x; }

// -------------------------------- init: zero cnt + W1,W2 -> W^T bf16
__global__ void init_kernel(const float* __restrict__ W1, const float* __restrict__ W2,
                            unsigned short* __restrict__ Wt1, unsigned short* __restrict__ Wt2,
                            int* __restrict__ cnt) {
    int idx = blockIdx.x * 256 + threadIdx.x;
    if (idx < N_NODES) cnt[idx] = 0;
    if (idx < 256 * F1) {
        int n = idx / 256, k = idx % 256;
        Wt1[idx] = f2bf(W1[(size_t)k * F1 + n]);
    } else {
        int j = idx - 256 * F1;
        if (j < 256 * F2) {
            int n = j / 256, k = j % 256;
            Wt2[j] = f2bf(W2[(size_t)k * F2 + n]);
        }
    }
}

// -------------------------------- bucket fill: no count/scan needed
__global__ void fill_kernel(const int* __restrict__ ei, int* __restrict__ cnt,
                            int* __restrict__ col) {
    int e = blockIdx.x * 256 + threadIdx.x;
    if (e >= EN_TOT) return;
    int src, dst;
    if (e < N_EDGES) { src = ei[e]; dst = ei[N_EDGES + e]; }
    else             { src = dst = e - N_EDGES; }
    int pos = atomicAdd(&cnt[dst], 1);
    if (pos < PAD) col[dst * PAD + pos] = src;
}

// ------------------------------------------- GEMM1 + fused alpha1 epilogue
// C_bf16[M,256] = f32 A[M,256] @ Wt1^T; blockIdx.y == head (cols head*128..+127).
// 4 waves, wave owns 32 rows x all 128 block cols -> in-wave alpha reduction.
__global__ __launch_bounds__(256)
void gemm1_kernel(const float* __restrict__ A, const unsigned short* __restrict__ Bt,
                  unsigned short* __restrict__ Cbf,
                  const float* __restrict__ a_src, const float* __restrict__ a_dst,
                  float* __restrict__ asrc, float* __restrict__ adst, int M) {
    constexpr int BM = 128, BN = 128, BK = 64, K = 256;
    constexpr int FM = 2, FN = 8;
    __shared__ short As[BM * BK];
    __shared__ short Bs[BN * BK];
    const int tid = threadIdx.x;
    const int lane = tid & 63, wid = tid >> 6;
    const int RW = wid * 32;
    const int head = blockIdx.y;
    const int brow = blockIdx.x * BM, bcol = head * BN;
    const int lr = lane & 15, lkg = lane >> 4;

    float4v acc[FM][FN];
    #pragma unroll
    for (int m = 0; m < FM; ++m)
        #pragma unroll
        for (int n = 0; n < FN; ++n) acc[m][n] = (float4v){0.f, 0.f, 0.f, 0.f};

    for (int k0 = 0; k0 < K; k0 += BK) {
        #pragma unroll
        for (int p = 0; p < BM * BK / 1024; ++p) {
            int flat = (p * 256 + tid) * 4;
            int r = flat / BK, kk = flat % BK;
            int gr = brow + r;
            float4 v = make_float4(0.f, 0.f, 0.f, 0.f);
            if (gr < M) v = *(const float4*)&A[(size_t)gr * K + k0 + kk];
            ushort4 o;
            o.x = f2bf(v.x); o.y = f2bf(v.y); o.z = f2bf(v.z); o.w = f2bf(v.w);
            *(ushort4*)((char*)As + r * (BK * 2) + ((kk * 2) ^ ((r & 7) << 4))) = o;
        }
        #pragma unroll
        for (int p = 0; p < BN * BK / 2048; ++p) {
            int flat = (p * 256 + tid) * 8;
            int r = flat / BK, kk = flat % BK;
            short8 v = *(const short8*)&Bt[(size_t)(bcol + r) * K + k0 + kk];
            *(short8*)((char*)Bs + r * (BK * 2) + ((kk * 2) ^ ((r & 7) << 4))) = v;
        }
        __syncthreads();
        #pragma unroll
        for (int ks = 0; ks < 2; ++ks) {
            short8 af[FM], bfr[FN];
            #pragma unroll
            for (int m = 0; m < FM; ++m) {
                int row = RW + m * 16 + lr;
                af[m] = *(const short8*)((const char*)As + row * (BK * 2) +
                        (((ks * 32 + lkg * 8) * 2) ^ ((row & 7) << 4)));
            }
            #pragma unroll
            for (int n = 0; n < FN; ++n) {
                int row = n * 16 + lr;
                bfr[n] = *(const short8*)((const char*)Bs + row * (BK * 2) +
                        (((ks * 32 + lkg * 8) * 2) ^ ((row & 7) << 4)));
            }
            #pragma unroll
            for (int m = 0; m < FM; ++m)
                #pragma unroll
                for (int n = 0; n < FN; ++n)
                    acc[m][n] = __builtin_amdgcn_mfma_f32_16x16x32_bf16(
                        af[m], bfr[n], acc[m][n], 0, 0, 0);
        }
        __syncthreads();
    }
    // epilogue: store bf16 h + fused alpha (dot over this block's 128 cols = head)
    const float* asv = a_src + head * 128;
    const float* adv = a_dst + head * 128;
    #pragma unroll
    for (int m = 0; m < FM; ++m) {
        #pragma unroll
        for (int j = 0; j < 4; ++j) {
            int row = brow + RW + m * 16 + lkg * 4 + j;
            if (row < M) {
                float ps = 0.f, pd = 0.f;
                #pragma unroll
                for (int n = 0; n < FN; ++n) {
                    float v = acc[m][n][j];
                    int c = n * 16 + lr;
                    Cbf[(size_t)row * F1 + bcol + c] = f2bf(v);
                    ps += v * asv[c];
                    pd += v * adv[c];
                }
                #pragma unroll
                for (int off = 1; off < 16; off <<= 1) {
                    ps += __shfl_xor(ps, off);
                    pd += __shfl_xor(pd, off);
                }
                if (lr == 0) {
                    asrc[row * 2 + head] = ps;
                    adst[row * 2 + head] = pd;
                }
            }
        }
    }
}

// ------------------------------------------- GEMM2 + fused alpha2 epilogue
__global__ __launch_bounds__(256)
void gemm2_kernel(const unsigned short* __restrict__ A, const unsigned short* __restrict__ Bt,
                  unsigned short* __restrict__ Cbf,
                  const float* __restrict__ a_src, const float* __restrict__ a_dst,
                  float* __restrict__ asrc, float* __restrict__ adst, int M) {
    constexpr int BM = 128, BN = 64, BK = 64, K = 256;
    constexpr int FM = 2, FN = 4;
    __shared__ short As[BM * BK];
    __shared__ short Bs[BN * BK];
    const int tid = threadIdx.x;
    const int lane = tid & 63, wid = tid >> 6;
    const int RW = wid * 32;
    const int brow = blockIdx.x * BM;
    const int lr = lane & 15, lkg = lane >> 4;

    float4v acc[FM][FN];
    #pragma unroll
    for (int m = 0; m < FM; ++m)
        #pragma unroll
        for (int n = 0; n < FN; ++n) acc[m][n] = (float4v){0.f, 0.f, 0.f, 0.f};

    for (int k0 = 0; k0 < K; k0 += BK) {
        #pragma unroll
        for (int p = 0; p < BM * BK / 2048; ++p) {
            int flat = (p * 256 + tid) * 8;
            int r = flat / BK, kk = flat % BK;
            int gr = brow + r;
            short8 v = {0, 0, 0, 0, 0, 0, 0, 0};
            if (gr < M) v = *(const short8*)&A[(size_t)gr * K + k0 + kk];
            *(short8*)((char*)As + r * (BK * 2) + ((kk * 2) ^ ((r & 7) << 4))) = v;
        }
        #pragma unroll
        for (int p = 0; p < BN * BK / 2048; ++p) {
            int flat = (p * 256 + tid) * 8;
            int r = flat / BK, kk = flat % BK;
            short8 v = *(const short8*)&Bt[(size_t)r * K + k0 + kk];
            *(short8*)((char*)Bs + r * (BK * 2) + ((kk * 2) ^ ((r & 7) << 4))) = v;
        }
        __syncthreads();
        #pragma unroll
        for (int ks = 0; ks < 2; ++ks) {
            short8 af[FM], bfr[FN];
            #pragma unroll
            for (int m = 0; m < FM; ++m) {
                int row = RW + m * 16 + lr;
                af[m] = *(const short8*)((const char*)As + row * (BK * 2) +
                        (((ks * 32 + lkg * 8) * 2) ^ ((row & 7) << 4)));
            }
            #pragma unroll
            for (int n = 0; n < FN; ++n) {
                int row = n * 16 + lr;
                bfr[n] = *(const short8*)((const char*)Bs + row * (BK * 2) +
                        (((ks * 32 + lkg * 8) * 2) ^ ((row & 7) << 4)));
            }
            #pragma unroll
            for (int m = 0; m < FM; ++m)
                #pragma unroll
                for (int n = 0; n < FN; ++n)
                    acc[m][n] = __builtin_amdgcn_mfma_f32_16x16x32_bf16(
                        af[m], bfr[n], acc[m][n], 0, 0, 0);
        }
        __syncthreads();
    }
    #pragma unroll
    for (int m = 0; m < FM; ++m) {
        #pragma unroll
        for (int j = 0; j < 4; ++j) {
            int row = brow + RW + m * 16 + lkg * 4 + j;
            if (row < M) {
                float ps = 0.f, pd = 0.f;
                #pragma unroll
                for (int n = 0; n < FN; ++n) {
                    float v = acc[m][n][j];
                    int c = n * 16 + lr;
                    Cbf[(size_t)row * F2 + c] = f2bf(v);
                    ps += v * a_src[c];
                    pd += v * a_dst[c];
                }
                #pragma unroll
                for (int off = 1; off < 16; off <<= 1) {
                    ps += __shfl_xor(ps, off);
                    pd += __shfl_xor(pd, off);
                }
                if (lr == 0) {
                    asrc[row] = ps;
                    adst[row] = pd;
                }
            }
        }
    }
}

// ---------------------------------------------------- layer-1 aggregation
// one WAVE per node (4 nodes/block), node range [n0, n0+span). fast path:
// halves of the wave process even/odd edges; lane owns 8 feats (ushort8).
__global__ __launch_bounds__(256)
void agg1_kernel(const unsigned short* __restrict__ h_bf,
                 const float* __restrict__ asrc, const float* __restrict__ adst,
                 const int* __restrict__ cnt, const int* __restrict__ col,
                 const float* __restrict__ b1, unsigned short* __restrict__ h1_bf,
                 int n0, int nend) {
    int n = n0 + blockIdx.x * 4 + (threadIdx.x >> 6);
    if (n >= nend) return;
    int lane = threadIdx.x & 63;
    int beg = n * PAD;
    int deg = min(cnt[n], PAD);
    int end = beg + deg;
    float ad0 = adst[2 * n], ad1 = adst[2 * n + 1];

    if (deg <= 64) {
        bool act = lane < deg;
        int src = 0; float e0 = -INFINITY, e1 = -INFINITY;
        if (act) {
            src = col[beg + lane];
            float2 av = *(const float2*)(asrc + 2 * src);
            e0 = lrelu(av.x + ad0); e1 = lrelu(av.y + ad1);
        }
        float m0 = e0, m1 = e1;
        #pragma unroll
        for (int off = 32; off; off >>= 1) {
            m0 = fmaxf(m0, __shfl_xor(m0, off));
            m1 = fmaxf(m1, __shfl_xor(m1, off));
        }
        float p0 = act ? __expf(e0 - m0) : 0.f;
        float p1 = act ? __expf(e1 - m1) : 0.f;
        float s0 = p0, s1 = p1;
        #pragma unroll
        for (int off = 32; off; off >>= 1) {
            s0 += __shfl_xor(s0, off);
            s1 += __shfl_xor(s1, off);
        }
        float w0 = p0 / s0, w1 = p1 / s1;

        int half = lane >> 5, fl = lane & 31;
        bool myhead = fl >= 16;                 // feats 8*fl..: head1 iff fl>=16
        float a[8] = {0.f, 0.f, 0.f, 0.f, 0.f, 0.f, 0.f, 0.f};
        for (int i = 0; i < deg; i += 2) {
            int ei = i + half;
            bool ok = ei < deg;
            int eidx = ok ? ei : 0;
            float wa = __shfl(w0, eidx), wb = __shfl(w1, eidx);
            int s = __shfl(src, eidx);
            float w = myhead ? wb : wa;
            if (!ok) w = 0.f;
            short8 v = *(const short8*)(h_bf + (size_t)s * F1 + fl * 8);
            #pragma unroll
            for (int j = 0; j < 8; ++j) a[j] += w * bf2f((unsigned short)v[j]);
        }
        #pragma unroll
        for (int j = 0; j < 8; ++j) a[j] += __shfl_xor(a[j], 32);
        if (half == 0) {
            float bb[8];
            *(float4*)&bb[0] = *(const float4*)(b1 + fl * 8);
            *(float4*)&bb[4] = *(const float4*)(b1 + fl * 8 + 4);
            short8 o;
            #pragma unroll
            for (int j = 0; j < 8; ++j) {
                float v = a[j] + bb[j];
                v = v > 0.f ? v : expm1f(v);
                o[j] = (short)f2bf(v);
            }
            *(short8*)(h1_bf + (size_t)n * F1 + fl * 8) = o;
        }
    } else {
        // general path (rare): per-edge 8B loads, lane owns 4 feats
        float a0 = 0.f, a1 = 0.f, a2 = 0.f, a3 = 0.f;
        float m0 = -INFINITY, s0 = 0.f, m1 = -INFINITY, s1 = 0.f;
        for (int k = beg + lane; k < end; k += 64) {
            int src = col[k];
            float2 av = *(const float2*)(asrc + 2 * src);
            float e0 = lrelu(av.x + ad0), e1 = lrelu(av.y + ad1);
            float nm = fmaxf(m0, e0); s0 = s0 * __expf(m0 - nm) + __expf(e0 - nm); m0 = nm;
            nm = fmaxf(m1, e1); s1 = s1 * __expf(m1 - nm) + __expf(e1 - nm); m1 = nm;
        }
        #pragma unroll
        for (int off = 32; off; off >>= 1) {
            float om = __shfl_xor(m0, off), os = __shfl_xor(s0, off);
            float nm = fmaxf(m0, om);
            s0 = (nm == -INFINITY) ? 0.f : (s0 * __expf(m0 - nm) + os * __expf(om - nm));
            m0 = nm;
            om = __shfl_xor(m1, off); os = __shfl_xor(s1, off);
            nm = fmaxf(m1, om);
            s1 = (nm == -INFINITY) ? 0.f : (s1 * __expf(m1 - nm) + os * __expf(om - nm));
            m1 = nm;
        }
        float i0 = 1.f / s0, i1 = 1.f / s1;
        for (int base = beg; base < end; base += 64) {
            int k = base + lane;
            bool act2 = k < end;
            int src = 0; float w0 = 0.f, w1 = 0.f;
            if (act2) {
                src = col[k];
                float2 av = *(const float2*)(asrc + 2 * src);
                w0 = __expf(lrelu(av.x + ad0) - m0) * i0;
                w1 = __expf(lrelu(av.y + ad1) - m1) * i1;
            }
            int cnt2 = min(64, end - base);
            for (int i = 0; i < cnt2; ++i) {
                float wa = __shfl(w0, i), wb = __shfl(w1, i);
                int s = __shfl(src, i);
                float w = (lane >= 32) ? wb : wa;
                ushort4 v = *(const ushort4*)(h_bf + (size_t)s * F1 + lane * 4);
                a0 += w * bf2f(v.x); a1 += w * bf2f(v.y);
                a2 += w * bf2f(v.z); a3 += w * bf2f(v.w);
            }
        }
        const float4 bb = *(const float4*)(b1 + lane * 4);
        float v0 = a0 + bb.x, v1 = a1 + bb.y, v2 = a2 + bb.z, v3 = a3 + bb.w;
        v0 = v0 > 0.f ? v0 : expm1f(v0);
        v1 = v1 > 0.f ? v1 : expm1f(v1);
        v2 = v2 > 0.f ? v2 : expm1f(v2);
        v3 = v3 > 0.f ? v3 : expm1f(v3);
        ushort4 o; o.x = f2bf(v0); o.y = f2bf(v1); o.z = f2bf(v2); o.w = f2bf(v3);
        *(ushort4*)(h1_bf + (size_t)n * F1 + lane * 4) = o;
    }
}

// ---------------------------------------------------- layer-2 aggregation
// 32-lane group per node (8 nodes / 256-thr block); fast path: 16-lane
// subgroups process even/odd edges, lane owns 4 feats (ushort4), xor(16).
__global__ __launch_bounds__(256)
void agg2_kernel(const unsigned short* __restrict__ g_bf,
                 const float* __restrict__ asrc, const float* __restrict__ adst,
                 const int* __restrict__ cnt, const int* __restrict__ col,
                 const float* __restrict__ b2, float* __restrict__ out) {
    int n = blockIdx.x * 8 + (threadIdx.x >> 5);
    if (n >= N_NODES) return;
    int l = threadIdx.x & 31;
    int lbase = threadIdx.x & 32;        // group offset within wave
    int beg = n * PAD;
    int deg = min(cnt[n], PAD);
    int end = beg + deg;
    float ad = adst[n];

    if (deg <= 32) {
        bool act = l < deg;
        int src = 0; float e = -INFINITY;
        if (act) {
            src = col[beg + l];
            e = lrelu(asrc[src] + ad);
        }
        float m = e;
        #pragma unroll
        for (int off = 16; off; off >>= 1) m = fmaxf(m, __shfl_xor(m, off));
        float p = act ? __expf(e - m) : 0.f;
        float s = p;
        #pragma unroll
        for (int off = 16; off; off >>= 1) s += __shfl_xor(s, off);
        float w = p / s;

        int sub = l >> 4, fl = l & 15;
        float a0 = 0.f, a1 = 0.f, a2 = 0.f, a3 = 0.f;
        for (int i = 0; i < deg; i += 2) {
            int ei = i + sub;
            bool ok = ei < deg;
            int eidx = ok ? ei : 0;
            float wi = __shfl(w, lbase + eidx);
            int si = __shfl(src, lbase + eidx);
            if (!ok) wi = 0.f;
            ushort4 v = *(const ushort4*)(g_bf + (size_t)si * F2 + fl * 4);
            a0 += wi * bf2f(v.x); a1 += wi * bf2f(v.y);
            a2 += wi * bf2f(v.z); a3 += wi * bf2f(v.w);
        }
        a0 += __shfl_xor(a0, 16); a1 += __shfl_xor(a1, 16);
        a2 += __shfl_xor(a2, 16); a3 += __shfl_xor(a3, 16);
        if (sub == 0) {
            float4 bb = *(const float4*)(b2 + fl * 4);
            float4 o;
            o.x = a0 + bb.x; o.y = a1 + bb.y; o.z = a2 + bb.z; o.w = a3 + bb.w;
            *(float4*)&out[(size_t)n * F2 + fl * 4] = o;
        }
    } else {
        float c0 = 0.f, c1 = 0.f;
        float m = -INFINITY, s = 0.f;
        for (int k = beg + l; k < end; k += 32) {
            int src = col[k];
            float e = lrelu(asrc[src] + ad);
            float nm = fmaxf(m, e);
            s = s * __expf(m - nm) + __expf(e - nm); m = nm;
        }
        #pragma unroll
        for (int off = 16; off; off >>= 1) {
            float om = __shfl_xor(m, off), os = __shfl_xor(s, off);
            float nm = fmaxf(m, om);
            s = (nm == -INFINITY) ? 0.f : (s * __expf(m - nm) + os * __expf(om - nm));
            m = nm;
        }
        float inv = 1.f / s;
        for (int base = beg; base < end; base += 32) {
            int k = base + l;
            bool act2 = k < end;
            int src = 0; float w = 0.f;
            if (act2) {
                src = col[k];
                w = __expf(lrelu(asrc[src] + ad) - m) * inv;
            }
            int cnt2 = min(32, end - base);
            for (int i = 0; i < cnt2; ++i) {
                float wi = __shfl(w, lbase + i);
                int si = __shfl(src, lbase + i);
                ushort2 v = *(const ushort2*)(g_bf + (size_t)si * F2 + l * 2);
                c0 += wi * bf2f(v.x);
                c1 += wi * bf2f(v.y);
            }
        }
        float2 bb = *(const float2*)(b2 + l * 2);
        float2 o; o.x = c0 + bb.x; o.y = c1 + bb.y;
        *(float2*)&out[(size_t)n * F2 + l * 2] = o;
    }
}

// ---------------------------------------------------------------- launch
extern "C" void kernel_launch(void* const* d_in, const int* in_sizes, int n_in,
                              void* d_out, int out_size, void* d_ws, size_t ws_size,
                              hipStream_t stream) {
    const float* x      = (const float*)d_in[0];
    const int*   ei     = (const int*)d_in[1];
    const float* W1     = (const float*)d_in[2];
    const float* a_src1 = (const float*)d_in[3];
    const float* a_dst1 = (const float*)d_in[4];
    const float* b1     = (const float*)d_in[5];
    const float* W2     = (const float*)d_in[6];
    const float* a_src2 = (const float*)d_in[7];
    const float* a_dst2 = (const float*)d_in[8];
    const float* b2     = (const float*)d_in[9];
    float* out = (float*)d_out;

    char* ws = (char*)d_ws;
    size_t off = 0;
    auto alloc = [&](size_t bytes) -> void* {
        void* p = ws + off;
        off = (off + bytes + 255) & ~(size_t)255;
        return p;
    };
    unsigned short* h_bf   = (unsigned short*)alloc((size_t)N_NODES * F1 * 2); // 25.6 MB
    unsigned short* h1_bf  = (unsigned short*)alloc((size_t)N_NODES * F1 * 2); // 25.6 MB
    unsigned short* g_bf   = (unsigned short*)alloc((size_t)N_NODES * F2 * 2); // 6.4 MB
    unsigned short* Wt1_bf = (unsigned short*)alloc((size_t)F1 * 256 * 2);
    unsigned short* Wt2_bf = (unsigned short*)alloc((size_t)F2 * 256 * 2);
    float* asrc1  = (float*)alloc((size_t)N_NODES * 2 * 4);
    float* adst1  = (float*)alloc((size_t)N_NODES * 2 * 4);
    float* asrc2  = (float*)alloc((size_t)N_NODES * 4);
    float* adst2  = (float*)alloc((size_t)N_NODES * 4);
    int*   cnt    = (int*)alloc((size_t)N_NODES * 4);
    int*   col    = (int*)alloc((size_t)N_NODES * PAD * 4); // 19.2 MB buckets

    const int eb = (EN_TOT + 255) / 256;
    const int ib = (256 * (F1 + F2) + 255) / 256;   // 320 >= 50000/256
    const int mb = (N_NODES + 127) / 128;   // 391
    const int nb8 = (N_NODES + 7) / 8;      // 6250

    init_kernel<<<ib, 256, 0, stream>>>(W1, W2, Wt1_bf, Wt2_bf, cnt);
    fill_kernel<<<eb, 256, 0, stream>>>(ei, cnt, col);

    gemm1_kernel<<<dim3(mb, 2), 256, 0, stream>>>(x, Wt1_bf, h_bf, a_src1, a_dst1,
                                                  asrc1, adst1, N_NODES);

    // agg1 split into 4 quarter-node launches (profiling visibility; same math)
    const int Q = (N_NODES + 3) / 4;            // 12500 nodes per quarter
    const int qb = (Q + 3) / 4;                 // 3125 blocks per quarter
    for (int q = 0; q < 4; ++q) {
        int n0 = q * Q;
        int nend = min(n0 + Q, N_NODES);
        agg1_kernel<<<qb, 256, 0, stream>>>(h_bf, asrc1, adst1, cnt, col, b1, h1_bf,
                                            n0, nend);
    }

    gemm2_kernel<<<mb, 256, 0, stream>>>(h1_bf, Wt2_bf, g_bf, a_src2, a_dst2,
                                         asrc2, adst2, N_NODES);
    agg2_kernel<<<nb8, 256, 0, stream>>>(g_bf, asrc2, adst2, cnt, col, b2, out);
}

// Round 12
// 182.035 us; speedup vs baseline: 1.2975x; 1.2975x over previous
//
#include <hip/hip_runtime.h>
#include <cmath>
#include <cstdint>
#include <cstddef>

#define N_NODES 50000
#define N_EDGES 800000
#define EN_TOT  (N_EDGES + N_NODES)   // edges + self loops
#define PAD     96                     // bucket capacity (Poisson(17): P(deg>96)~1e-40)
#define F1 256                         // HEADS*HID
#define F2 64                          // OUT

typedef __attribute__((ext_vector_type(8))) short short8;
typedef __attribute__((ext_vector_type(4))) float float4v;

__device__ __forceinline__ float bf2f(unsigned short u) {
    return __uint_as_float((unsigned)u << 16);
}
__device__ __forceinline__ unsigned short f2bf(float f) {
    unsigned u = __float_as_uint(f);
    unsigned r = (u + 0x7FFFu + ((u >> 16) & 1u)) >> 16;   // round-nearest-even
    return (unsigned short)r;
}
__device__ __forceinline__ float lrelu(float x) { return x > 0.f ? x : 0.2f * x; }

// -------------------------------- init: W1,W2 -> W^T bf16 (cnt zeroed by memset)
__global__ void init_kernel(const float* __restrict__ W1, const float* __restrict__ W2,
                            unsigned short* __restrict__ Wt1, unsigned short* __restrict__ Wt2) {
    int idx = blockIdx.x * 256 + threadIdx.x;
    if (idx < 256 * F1) {
        int n = idx / 256, k = idx % 256;
        Wt1[idx] = f2bf(W1[(size_t)k * F1 + n]);
    } else {
        int j = idx - 256 * F1;
        if (j < 256 * F2) {
            int n = j / 256, k = j % 256;
            Wt2[j] = f2bf(W2[(size_t)k * F2 + n]);
        }
    }
}

// ----------------------- MEGA: gemm1(+alpha1) blocks || bucket-fill blocks
// blocks [0,782): gemm1 body (391 row-tiles x 2 heads) — needs Wt1 (init).
// blocks [782, 782+3321): fill body — needs cnt=0 (memset). Independent work
// co-scheduled so fill's latency hides under gemm1's MFMA.
#define GEMM_BLOCKS 782
__global__ __launch_bounds__(256)
void mega1_kernel(const float* __restrict__ A, const unsigned short* __restrict__ Bt,
                  unsigned short* __restrict__ Cbf,
                  const float* __restrict__ a_src, const float* __restrict__ a_dst,
                  float* __restrict__ asrc, float* __restrict__ adst, int M,
                  const int* __restrict__ ei, int* __restrict__ cnt,
                  int* __restrict__ col) {
    if (blockIdx.x >= GEMM_BLOCKS) {
        // ---------------- fill role
        int e = (blockIdx.x - GEMM_BLOCKS) * 256 + threadIdx.x;
        if (e < EN_TOT) {
            int src, dst;
            if (e < N_EDGES) { src = ei[e]; dst = ei[N_EDGES + e]; }
            else             { src = dst = e - N_EDGES; }
            int pos = atomicAdd(&cnt[dst], 1);
            if (pos < PAD) col[dst * PAD + pos] = src;
        }
        return;
    }
    // ---------------- gemm1 role
    constexpr int BM = 128, BN = 128, BK = 64, K = 256;
    constexpr int FM = 2, FN = 8;
    __shared__ short As[BM * BK];
    __shared__ short Bs[BN * BK];
    const int tid = threadIdx.x;
    const int lane = tid & 63, wid = tid >> 6;
    const int RW = wid * 32;
    const int head = blockIdx.x & 1;
    const int brow = (blockIdx.x >> 1) * BM, bcol = head * BN;
    const int lr = lane & 15, lkg = lane >> 4;

    float4v acc[FM][FN];
    #pragma unroll
    for (int m = 0; m < FM; ++m)
        #pragma unroll
        for (int n = 0; n < FN; ++n) acc[m][n] = (float4v){0.f, 0.f, 0.f, 0.f};

    for (int k0 = 0; k0 < K; k0 += BK) {
        #pragma unroll
        for (int p = 0; p < BM * BK / 1024; ++p) {
            int flat = (p * 256 + tid) * 4;
            int r = flat / BK, kk = flat % BK;
            int gr = brow + r;
            float4 v = make_float4(0.f, 0.f, 0.f, 0.f);
            if (gr < M) v = *(const float4*)&A[(size_t)gr * K + k0 + kk];
            ushort4 o;
            o.x = f2bf(v.x); o.y = f2bf(v.y); o.z = f2bf(v.z); o.w = f2bf(v.w);
            *(ushort4*)((char*)As + r * (BK * 2) + ((kk * 2) ^ ((r & 7) << 4))) = o;
        }
        #pragma unroll
        for (int p = 0; p < BN * BK / 2048; ++p) {
            int flat = (p * 256 + tid) * 8;
            int r = flat / BK, kk = flat % BK;
            short8 v = *(const short8*)&Bt[(size_t)(bcol + r) * K + k0 + kk];
            *(short8*)((char*)Bs + r * (BK * 2) + ((kk * 2) ^ ((r & 7) << 4))) = v;
        }
        __syncthreads();
        #pragma unroll
        for (int ks = 0; ks < 2; ++ks) {
            short8 af[FM], bfr[FN];
            #pragma unroll
            for (int m = 0; m < FM; ++m) {
                int row = RW + m * 16 + lr;
                af[m] = *(const short8*)((const char*)As + row * (BK * 2) +
                        (((ks * 32 + lkg * 8) * 2) ^ ((row & 7) << 4)));
            }
            #pragma unroll
            for (int n = 0; n < FN; ++n) {
                int row = n * 16 + lr;
                bfr[n] = *(const short8*)((const char*)Bs + row * (BK * 2) +
                        (((ks * 32 + lkg * 8) * 2) ^ ((row & 7) << 4)));
            }
            #pragma unroll
            for (int m = 0; m < FM; ++m)
                #pragma unroll
                for (int n = 0; n < FN; ++n)
                    acc[m][n] = __builtin_amdgcn_mfma_f32_16x16x32_bf16(
                        af[m], bfr[n], acc[m][n], 0, 0, 0);
        }
        __syncthreads();
    }
    // epilogue: store bf16 h + fused alpha (dot over this block's 128 cols = head)
    const float* asv = a_src + head * 128;
    const float* adv = a_dst + head * 128;
    #pragma unroll
    for (int m = 0; m < FM; ++m) {
        #pragma unroll
        for (int j = 0; j < 4; ++j) {
            int row = brow + RW + m * 16 + lkg * 4 + j;
            if (row < M) {
                float ps = 0.f, pd = 0.f;
                #pragma unroll
                for (int n = 0; n < FN; ++n) {
                    float v = acc[m][n][j];
                    int c = n * 16 + lr;
                    Cbf[(size_t)row * F1 + bcol + c] = f2bf(v);
                    ps += v * asv[c];
                    pd += v * adv[c];
                }
                #pragma unroll
                for (int off = 1; off < 16; off <<= 1) {
                    ps += __shfl_xor(ps, off);
                    pd += __shfl_xor(pd, off);
                }
                if (lr == 0) {
                    asrc[row * 2 + head] = ps;
                    adst[row * 2 + head] = pd;
                }
            }
        }
    }
}

// ------------------------------------------- GEMM2 + fused alpha2 epilogue
__global__ __launch_bounds__(256)
void gemm2_kernel(const unsigned short* __restrict__ A, const unsigned short* __restrict__ Bt,
                  unsigned short* __restrict__ Cbf,
                  const float* __restrict__ a_src, const float* __restrict__ a_dst,
                  float* __restrict__ asrc, float* __restrict__ adst, int M) {
    constexpr int BM = 128, BN = 64, BK = 64, K = 256;
    constexpr int FM = 2, FN = 4;
    __shared__ short As[BM * BK];
    __shared__ short Bs[BN * BK];
    const int tid = threadIdx.x;
    const int lane = tid & 63, wid = tid >> 6;
    const int RW = wid * 32;
    const int brow = blockIdx.x * BM;
    const int lr = lane & 15, lkg = lane >> 4;

    float4v acc[FM][FN];
    #pragma unroll
    for (int m = 0; m < FM; ++m)
        #pragma unroll
        for (int n = 0; n < FN; ++n) acc[m][n] = (float4v){0.f, 0.f, 0.f, 0.f};

    for (int k0 = 0; k0 < K; k0 += BK) {
        #pragma unroll
        for (int p = 0; p < BM * BK / 2048; ++p) {
            int flat = (p * 256 + tid) * 8;
            int r = flat / BK, kk = flat % BK;
            int gr = brow + r;
            short8 v = {0, 0, 0, 0, 0, 0, 0, 0};
            if (gr < M) v = *(const short8*)&A[(size_t)gr * K + k0 + kk];
            *(short8*)((char*)As + r * (BK * 2) + ((kk * 2) ^ ((r & 7) << 4))) = v;
        }
        #pragma unroll
        for (int p = 0; p < BN * BK / 2048; ++p) {
            int flat = (p * 256 + tid) * 8;
            int r = flat / BK, kk = flat % BK;
            short8 v = *(const short8*)&Bt[(size_t)r * K + k0 + kk];
            *(short8*)((char*)Bs + r * (BK * 2) + ((kk * 2) ^ ((r & 7) << 4))) = v;
        }
        __syncthreads();
        #pragma unroll
        for (int ks = 0; ks < 2; ++ks) {
            short8 af[FM], bfr[FN];
            #pragma unroll
            for (int m = 0; m < FM; ++m) {
                int row = RW + m * 16 + lr;
                af[m] = *(const short8*)((const char*)As + row * (BK * 2) +
                        (((ks * 32 + lkg * 8) * 2) ^ ((row & 7) << 4)));
            }
            #pragma unroll
            for (int n = 0; n < FN; ++n) {
                int row = n * 16 + lr;
                bfr[n] = *(const short8*)((const char*)Bs + row * (BK * 2) +
                        (((ks * 32 + lkg * 8) * 2) ^ ((row & 7) << 4)));
            }
            #pragma unroll
            for (int m = 0; m < FM; ++m)
                #pragma unroll
                for (int n = 0; n < FN; ++n)
                    acc[m][n] = __builtin_amdgcn_mfma_f32_16x16x32_bf16(
                        af[m], bfr[n], acc[m][n], 0, 0, 0);
        }
        __syncthreads();
    }
    #pragma unroll
    for (int m = 0; m < FM; ++m) {
        #pragma unroll
        for (int j = 0; j < 4; ++j) {
            int row = brow + RW + m * 16 + lkg * 4 + j;
            if (row < M) {
                float ps = 0.f, pd = 0.f;
                #pragma unroll
                for (int n = 0; n < FN; ++n) {
                    float v = acc[m][n][j];
                    int c = n * 16 + lr;
                    Cbf[(size_t)row * F2 + c] = f2bf(v);
                    ps += v * a_src[c];
                    pd += v * a_dst[c];
                }
                #pragma unroll
                for (int off = 1; off < 16; off <<= 1) {
                    ps += __shfl_xor(ps, off);
                    pd += __shfl_xor(pd, off);
                }
                if (lr == 0) {
                    asrc[row] = ps;
                    adst[row] = pd;
                }
            }
        }
    }
}

// ---------------------------------------------------- layer-1 aggregation
// one WAVE per node (4 nodes/block). fast path: halves of the wave process
// even/odd edges; lane owns 8 feats, loads ushort8 (16B); xor(32) combine.
__global__ __launch_bounds__(256)
void agg1_kernel(const unsigned short* __restrict__ h_bf,
                 const float* __restrict__ asrc, const float* __restrict__ adst,
                 const int* __restrict__ cnt, const int* __restrict__ col,
                 const float* __restrict__ b1, unsigned short* __restrict__ h1_bf) {
    int n = blockIdx.x * 4 + (threadIdx.x >> 6);
    if (n >= N_NODES) return;
    int lane = threadIdx.x & 63;
    int beg = n * PAD;
    int deg = min(cnt[n], PAD);
    int end = beg + deg;
    float ad0 = adst[2 * n], ad1 = adst[2 * n + 1];

    if (deg <= 64) {
        bool act = lane < deg;
        int src = 0; float e0 = -INFINITY, e1 = -INFINITY;
        if (act) {
            src = col[beg + lane];
            float2 av = *(const float2*)(asrc + 2 * src);
            e0 = lrelu(av.x + ad0); e1 = lrelu(av.y + ad1);
        }
        float m0 = e0, m1 = e1;
        #pragma unroll
        for (int off = 32; off; off >>= 1) {
            m0 = fmaxf(m0, __shfl_xor(m0, off));
            m1 = fmaxf(m1, __shfl_xor(m1, off));
        }
        float p0 = act ? __expf(e0 - m0) : 0.f;
        float p1 = act ? __expf(e1 - m1) : 0.f;
        float s0 = p0, s1 = p1;
        #pragma unroll
        for (int off = 32; off; off >>= 1) {
            s0 += __shfl_xor(s0, off);
            s1 += __shfl_xor(s1, off);
        }
        float w0 = p0 / s0, w1 = p1 / s1;

        int half = lane >> 5, fl = lane & 31;
        bool myhead = fl >= 16;                 // feats 8*fl..: head1 iff fl>=16
        float a[8] = {0.f, 0.f, 0.f, 0.f, 0.f, 0.f, 0.f, 0.f};
        for (int i = 0; i < deg; i += 2) {
            int ei = i + half;
            bool ok = ei < deg;
            int eidx = ok ? ei : 0;
            float wa = __shfl(w0, eidx), wb = __shfl(w1, eidx);
            int s = __shfl(src, eidx);
            float w = myhead ? wb : wa;
            if (!ok) w = 0.f;
            short8 v = *(const short8*)(h_bf + (size_t)s * F1 + fl * 8);
            #pragma unroll
            for (int j = 0; j < 8; ++j) a[j] += w * bf2f((unsigned short)v[j]);
        }
        #pragma unroll
        for (int j = 0; j < 8; ++j) a[j] += __shfl_xor(a[j], 32);
        if (half == 0) {
            float bb[8];
            *(float4*)&bb[0] = *(const float4*)(b1 + fl * 8);
            *(float4*)&bb[4] = *(const float4*)(b1 + fl * 8 + 4);
            short8 o;
            #pragma unroll
            for (int j = 0; j < 8; ++j) {
                float v = a[j] + bb[j];
                v = v > 0.f ? v : expm1f(v);
                o[j] = (short)f2bf(v);
            }
            *(short8*)(h1_bf + (size_t)n * F1 + fl * 8) = o;
        }
    } else {
        // general path (rare): per-edge 8B loads, lane owns 4 feats
        float a0 = 0.f, a1 = 0.f, a2 = 0.f, a3 = 0.f;
        float m0 = -INFINITY, s0 = 0.f, m1 = -INFINITY, s1 = 0.f;
        for (int k = beg + lane; k < end; k += 64) {
            int src = col[k];
            float2 av = *(const float2*)(asrc + 2 * src);
            float e0 = lrelu(av.x + ad0), e1 = lrelu(av.y + ad1);
            float nm = fmaxf(m0, e0); s0 = s0 * __expf(m0 - nm) + __expf(e0 - nm); m0 = nm;
            nm = fmaxf(m1, e1); s1 = s1 * __expf(m1 - nm) + __expf(e1 - nm); m1 = nm;
        }
        #pragma unroll
        for (int off = 32; off; off >>= 1) {
            float om = __shfl_xor(m0, off), os = __shfl_xor(s0, off);
            float nm = fmaxf(m0, om);
            s0 = (nm == -INFINITY) ? 0.f : (s0 * __expf(m0 - nm) + os * __expf(om - nm));
            m0 = nm;
            om = __shfl_xor(m1, off); os = __shfl_xor(s1, off);
            nm = fmaxf(m1, om);
            s1 = (nm == -INFINITY) ? 0.f : (s1 * __expf(m1 - nm) + os * __expf(om - nm));
            m1 = nm;
        }
        float i0 = 1.f / s0, i1 = 1.f / s1;
        for (int base = beg; base < end; base += 64) {
            int k = base + lane;
            bool act2 = k < end;
            int src = 0; float w0 = 0.f, w1 = 0.f;
            if (act2) {
                src = col[k];
                float2 av = *(const float2*)(asrc + 2 * src);
                w0 = __expf(lrelu(av.x + ad0) - m0) * i0;
                w1 = __expf(lrelu(av.y + ad1) - m1) * i1;
            }
            int cnt2 = min(64, end - base);
            for (int i = 0; i < cnt2; ++i) {
                float wa = __shfl(w0, i), wb = __shfl(w1, i);
                int s = __shfl(src, i);
                float w = (lane >= 32) ? wb : wa;
                ushort4 v = *(const ushort4*)(h_bf + (size_t)s * F1 + lane * 4);
                a0 += w * bf2f(v.x); a1 += w * bf2f(v.y);
                a2 += w * bf2f(v.z); a3 += w * bf2f(v.w);
            }
        }
        const float4 bb = *(const float4*)(b1 + lane * 4);
        float v0 = a0 + bb.x, v1 = a1 + bb.y, v2 = a2 + bb.z, v3 = a3 + bb.w;
        v0 = v0 > 0.f ? v0 : expm1f(v0);
        v1 = v1 > 0.f ? v1 : expm1f(v1);
        v2 = v2 > 0.f ? v2 : expm1f(v2);
        v3 = v3 > 0.f ? v3 : expm1f(v3);
        ushort4 o; o.x = f2bf(v0); o.y = f2bf(v1); o.z = f2bf(v2); o.w = f2bf(v3);
        *(ushort4*)(h1_bf + (size_t)n * F1 + lane * 4) = o;
    }
}

// ---------------------------------------------------- layer-2 aggregation
// 32-lane group per node (8 nodes / 256-thr block); fast path: 16-lane
// subgroups process even/odd edges, lane owns 4 feats (ushort4), xor(16).
__global__ __launch_bounds__(256)
void agg2_kernel(const unsigned short* __restrict__ g_bf,
                 const float* __restrict__ asrc, const float* __restrict__ adst,
                 const int* __restrict__ cnt, const int* __restrict__ col,
                 const float* __restrict__ b2, float* __restrict__ out) {
    int n = blockIdx.x * 8 + (threadIdx.x >> 5);
    if (n >= N_NODES) return;
    int l = threadIdx.x & 31;
    int lbase = threadIdx.x & 32;        // group offset within wave
    int beg = n * PAD;
    int deg = min(cnt[n], PAD);
    int end = beg + deg;
    float ad = adst[n];

    if (deg <= 32) {
        bool act = l < deg;
        int src = 0; float e = -INFINITY;
        if (act) {
            src = col[beg + l];
            e = lrelu(asrc[src] + ad);
        }
        float m = e;
        #pragma unroll
        for (int off = 16; off; off >>= 1) m = fmaxf(m, __shfl_xor(m, off));
        float p = act ? __expf(e - m) : 0.f;
        float s = p;
        #pragma unroll
        for (int off = 16; off; off >>= 1) s += __shfl_xor(s, off);
        float w = p / s;

        int sub = l >> 4, fl = l & 15;
        float a0 = 0.f, a1 = 0.f, a2 = 0.f, a3 = 0.f;
        for (int i = 0; i < deg; i += 2) {
            int ei = i + sub;
            bool ok = ei < deg;
            int eidx = ok ? ei : 0;
            float wi = __shfl(w, lbase + eidx);
            int si = __shfl(src, lbase + eidx);
            if (!ok) wi = 0.f;
            ushort4 v = *(const ushort4*)(g_bf + (size_t)si * F2 + fl * 4);
            a0 += wi * bf2f(v.x); a1 += wi * bf2f(v.y);
            a2 += wi * bf2f(v.z); a3 += wi * bf2f(v.w);
        }
        a0 += __shfl_xor(a0, 16); a1 += __shfl_xor(a1, 16);
        a2 += __shfl_xor(a2, 16); a3 += __shfl_xor(a3, 16);
        if (sub == 0) {
            float4 bb = *(const float4*)(b2 + fl * 4);
            float4 o;
            o.x = a0 + bb.x; o.y = a1 + bb.y; o.z = a2 + bb.z; o.w = a3 + bb.w;
            *(float4*)&out[(size_t)n * F2 + fl * 4] = o;
        }
    } else {
        float c0 = 0.f, c1 = 0.f;
        float m = -INFINITY, s = 0.f;
        for (int k = beg + l; k < end; k += 32) {
            int src = col[k];
            float e = lrelu(asrc[src] + ad);
            float nm = fmaxf(m, e);
            s = s * __expf(m - nm) + __expf(e - nm); m = nm;
        }
        #pragma unroll
        for (int off = 16; off; off >>= 1) {
            float om = __shfl_xor(m, off), os = __shfl_xor(s, off);
            float nm = fmaxf(m, om);
            s = (nm == -INFINITY) ? 0.f : (s * __expf(m - nm) + os * __expf(om - nm));
            m = nm;
        }
        float inv = 1.f / s;
        for (int base = beg; base < end; base += 32) {
            int k = base + l;
            bool act2 = k < end;
            int src = 0; float w = 0.f;
            if (act2) {
                src = col[k];
                w = __expf(lrelu(asrc[src] + ad) - m) * inv;
            }
            int cnt2 = min(32, end - base);
            for (int i = 0; i < cnt2; ++i) {
                float wi = __shfl(w, lbase + i);
                int si = __shfl(src, lbase + i);
                ushort2 v = *(const ushort2*)(g_bf + (size_t)si * F2 + l * 2);
                c0 += wi * bf2f(v.x);
                c1 += wi * bf2f(v.y);
            }
        }
        float2 bb = *(const float2*)(b2 + l * 2);
        float2 o; o.x = c0 + bb.x; o.y = c1 + bb.y;
        *(float2*)&out[(size_t)n * F2 + l * 2] = o;
    }
}

// ---------------------------------------------------------------- launch
extern "C" void kernel_launch(void* const* d_in, const int* in_sizes, int n_in,
                              void* d_out, int out_size, void* d_ws, size_t ws_size,
                              hipStream_t stream) {
    const float* x      = (const float*)d_in[0];
    const int*   ei     = (const int*)d_in[1];
    const float* W1     = (const float*)d_in[2];
    const float* a_src1 = (const float*)d_in[3];
    const float* a_dst1 = (const float*)d_in[4];
    const float* b1     = (const float*)d_in[5];
    const float* W2     = (const float*)d_in[6];
    const float* a_src2 = (const float*)d_in[7];
    const float* a_dst2 = (const float*)d_in[8];
    const float* b2     = (const float*)d_in[9];
    float* out = (float*)d_out;

    char* ws = (char*)d_ws;
    size_t off = 0;
    auto alloc = [&](size_t bytes) -> void* {
        void* p = ws + off;
        off = (off + bytes + 255) & ~(size_t)255;
        return p;
    };
    unsigned short* h_bf   = (unsigned short*)alloc((size_t)N_NODES * F1 * 2); // 25.6 MB
    unsigned short* h1_bf  = (unsigned short*)alloc((size_t)N_NODES * F1 * 2); // 25.6 MB
    unsigned short* g_bf   = (unsigned short*)alloc((size_t)N_NODES * F2 * 2); // 6.4 MB
    unsigned short* Wt1_bf = (unsigned short*)alloc((size_t)F1 * 256 * 2);
    unsigned short* Wt2_bf = (unsigned short*)alloc((size_t)F2 * 256 * 2);
    float* asrc1  = (float*)alloc((size_t)N_NODES * 2 * 4);
    float* adst1  = (float*)alloc((size_t)N_NODES * 2 * 4);
    float* asrc2  = (float*)alloc((size_t)N_NODES * 4);
    float* adst2  = (float*)alloc((size_t)N_NODES * 4);
    int*   cnt    = (int*)alloc((size_t)N_NODES * 4);
    int*   col    = (int*)alloc((size_t)N_NODES * PAD * 4); // 19.2 MB buckets

    const int fb = (EN_TOT + 255) / 256;            // 3321 fill blocks
    const int ib = (256 * (F1 + F2) + 255) / 256;   // 320 init blocks
    const int mb = (N_NODES + 127) / 128;   // 391
    const int nb4 = (N_NODES + 3) / 4;      // 12500
    const int nb8 = (N_NODES + 7) / 8;      // 6250

    hipMemsetAsync(cnt, 0, (size_t)N_NODES * 4, stream);
    init_kernel<<<ib, 256, 0, stream>>>(W1, W2, Wt1_bf, Wt2_bf);

    mega1_kernel<<<GEMM_BLOCKS + fb, 256, 0, stream>>>(
        x, Wt1_bf, h_bf, a_src1, a_dst1, asrc1, adst1, N_NODES, ei, cnt, col);

    agg1_kernel<<<nb4, 256, 0, stream>>>(h_bf, asrc1, adst1, cnt, col, b1, h1_bf);

    gemm2_kernel<<<mb, 256, 0, stream>>>(h1_bf, Wt2_bf, g_bf, a_src2, a_dst2,
                                         asrc2, adst2, N_NODES);
    agg2_kernel<<<nb8, 256, 0, stream>>>(g_bf, asrc2, adst2, cnt, col, b2, out);
}